// Round 1
// baseline (431.136 us; speedup 1.0000x reference)
//
#include <hip/hip_runtime.h>

#define NUM_JOINTS 50
#define NUM_BONES  50
#define FEAT       150
#define FRAMES_PER_BLOCK 32
#define THREADS    256
#define TILE_ELEMS (FRAMES_PER_BLOCK * FEAT)   // 4800 floats per tensor
#define TINY_F     1.17549435e-38f             // np.finfo(float32).tiny

// 50-bone skeleton (body + two 21-bone hands + pad bone (0,2))
__device__ __constant__ int c_ba[NUM_BONES] = {
    0, 1, 2, 3, 1, 5, 6,                                    // body
    7, 8, 9, 10, 11, 8, 13, 14, 15, 8, 17, 18, 19,
    8, 21, 22, 23, 8, 25, 26, 27,                           // hand 1
    4, 29, 30, 31, 32, 29, 34, 35, 36, 29, 38, 39, 40,
    29, 42, 43, 44, 29, 46, 47, 48,                         // hand 2
    0                                                       // pad
};
__device__ __constant__ int c_bb[NUM_BONES] = {
    1, 2, 3, 4, 5, 6, 7,
    8, 9, 10, 11, 12, 13, 14, 15, 16, 17, 18, 19, 20,
    21, 22, 23, 24, 25, 26, 27, 28,
    29, 30, 31, 32, 33, 34, 35, 36, 37, 38, 39, 40, 41,
    42, 43, 44, 45, 46, 47, 48, 49,
    2
};

__global__ __launch_bounds__(THREADS)
void loss_main(const float* __restrict__ preds,
               const float* __restrict__ targets,
               double* __restrict__ sums)
{
    __shared__ float s_pm[TILE_ELEMS];
    __shared__ float s_tm[TILE_ELEMS];

    const int tid  = threadIdx.x;
    const long long base = (long long)blockIdx.x * TILE_ELEMS;

    // ---- Phase 1: coalesced float4 load, mask, L1 term, stage to LDS ----
    const float4* p4 = (const float4*)(preds + base);
    const float4* t4 = (const float4*)(targets + base);
    float4* spm4 = (float4*)s_pm;
    float4* stm4 = (float4*)s_tm;

    float l1 = 0.0f;
    const int n4 = TILE_ELEMS / 4;  // 1200
    for (int i = tid; i < n4; i += THREADS) {
        float4 p = p4[i];
        float4 t = t4[i];
        float4 pm, tm;
        pm.x = (t.x != 0.0f) ? p.x : 0.0f;  tm.x = (t.x != 0.0f) ? t.x : 0.0f;
        pm.y = (t.y != 0.0f) ? p.y : 0.0f;  tm.y = (t.y != 0.0f) ? t.y : 0.0f;
        pm.z = (t.z != 0.0f) ? p.z : 0.0f;  tm.z = (t.z != 0.0f) ? t.z : 0.0f;
        pm.w = (t.w != 0.0f) ? p.w : 0.0f;  tm.w = (t.w != 0.0f) ? t.w : 0.0f;
        l1 += fabsf(pm.x - tm.x) + fabsf(pm.y - tm.y)
            + fabsf(pm.z - tm.z) + fabsf(pm.w - tm.w);
        spm4[i] = pm;
        stm4[i] = tm;
    }
    __syncthreads();

    // ---- Phase 2: bone directions + masked MSE term ----
    float mse = 0.0f;
    const int ntask = FRAMES_PER_BLOCK * NUM_BONES;  // 1600
    for (int i = tid; i < ntask; i += THREADS) {
        const int f = i / NUM_BONES;
        const int b = i - f * NUM_BONES;
        const float* pm = s_pm + f * FEAT;
        const float* tm = s_tm + f * FEAT;
        const int ja = 3 * c_ba[b];
        const int jb = 3 * c_bb[b];

        float dpx = pm[ja]     - pm[jb];
        float dpy = pm[ja + 1] - pm[jb + 1];
        float dpz = pm[ja + 2] - pm[jb + 2];
        float dtx = tm[ja]     - tm[jb];
        float dty = tm[ja + 1] - tm[jb + 1];
        float dtz = tm[ja + 2] - tm[jb + 2];

        float lp = sqrtf(dpx * dpx + dpy * dpy + dpz * dpz);
        float lt = sqrtf(dtx * dtx + dty * dty + dtz * dtz);
        float ip = 1.0f / (lp + TINY_F);
        float it = 1.0f / (lt + TINY_F);

        const int o = 3 * b;
        // mask at direct-output index == (tm element != 0); m^2 == m
        float e0 = dpx * ip - dtx * it;
        float e1 = dpy * ip - dty * it;
        float e2 = dpz * ip - dtz * it;
        if (tm[o]     != 0.0f) mse += e0 * e0;
        if (tm[o + 1] != 0.0f) mse += e1 * e1;
        if (tm[o + 2] != 0.0f) mse += e2 * e2;
    }

    // ---- Block reduction (double) ----
    double v0 = (double)l1;
    double v1 = (double)mse;
    for (int off = 32; off > 0; off >>= 1) {
        v0 += __shfl_down(v0, off, 64);
        v1 += __shfl_down(v1, off, 64);
    }
    __shared__ double s_red0[THREADS / 64];
    __shared__ double s_red1[THREADS / 64];
    const int wave = tid >> 6;
    const int lane = tid & 63;
    if (lane == 0) { s_red0[wave] = v0; s_red1[wave] = v1; }
    __syncthreads();
    if (tid == 0) {
        double a = s_red0[0] + s_red0[1] + s_red0[2] + s_red0[3];
        double b = s_red1[0] + s_red1[1] + s_red1[2] + s_red1[3];
        atomicAdd(&sums[0], a);
        atomicAdd(&sums[1], b);
    }
}

__global__ void loss_final(const double* __restrict__ sums,
                           float* __restrict__ out)
{
    const double N = 64.0 * 4096.0 * 150.0;  // 39,321,600 (both means)
    out[0] = (float)(sums[0] / N + 0.1 * (sums[1] / N));
}

extern "C" void kernel_launch(void* const* d_in, const int* in_sizes, int n_in,
                              void* d_out, int out_size, void* d_ws, size_t ws_size,
                              hipStream_t stream)
{
    (void)in_sizes; (void)n_in; (void)out_size; (void)ws_size;
    const float* preds   = (const float*)d_in[0];
    const float* targets = (const float*)d_in[1];
    double* sums = (double*)d_ws;

    hipMemsetAsync(d_ws, 0, 2 * sizeof(double), stream);

    const int tiles = (64 * 4096) / FRAMES_PER_BLOCK;  // 8192
    loss_main<<<tiles, THREADS, 0, stream>>>(preds, targets, sums);
    loss_final<<<1, 1, 0, stream>>>(sums, (float*)d_out);
}